// Round 1
// 221.664 us; speedup vs baseline: 1.0902x; 1.0902x over previous
//
#include <hip/hip_runtime.h>

// CropConv on MI355X: mask degenerates to all-True -> pure stride-2 3x3 conv.
// Implicit GEMM: M=COUT=256, N=B*OH*OW=32768, K=CIN*9=2304, f16 MFMA 32x32x16.
//
// R1: software-pipelined K-loop (T14 async-stage split). Prefetch cc+1 into
// registers while computing cc from LDS only; xs double-buffered (writes into
// idle buffer, no WAR barrier); ws single-buffered via reg round-trip between
// the two barriers; +16B inter-plane pad kills the staging-write bank
// conflicts; setprio(1) around the MFMA cluster.

#define B_   32
#define CIN  256
#define COUT 256
#define H_   64
#define W_   64
#define OH   32
#define OW   32

typedef _Float16 f16;
typedef _Float16 half8 __attribute__((ext_vector_type(8)));
typedef float    floatx16 __attribute__((ext_vector_type(16)));

// Pre-pass: repack fp32 weights [256][256][3][3] -> f16 in d_ws with layout
// [co_t 2][cc 16][khw 9][co_l 128][ci_l 16]  (1,179,648 B)
__global__ __launch_bounds__(256) void repack_w_kernel(const float* __restrict__ w,
                                                       f16* __restrict__ rp) {
  int o = blockIdx.x * 256 + threadIdx.x;     // 589824 total, exact
  int ci_l = o & 15;
  int tt = o >> 4;
  int co_l = tt & 127; tt >>= 7;
  int khw = tt % 9;    tt /= 9;
  int cc   = tt & 15;  tt >>= 4;
  int co_t = tt;                               // 0..1
  int co = co_t * 128 + co_l;
  int ci = cc * 16 + ci_l;
  rp[o] = (f16)w[(co * CIN + ci) * 9 + khw];
}

#define XSP   (9 * 33 * 16)   // one x plane: 4752 f16
#define XSP1  (XSP + 8)       // plane1 offset: +16B pad shifts bank-slot parity
#define XSBUF (XSP1 + XSP)    // 9512 f16 per buffer (19024 B)

// Main: each block computes out[b][co_t*128 .. +128)[oh0 .. oh0+4)[0..32)
// 4 waves, 64co x 64n per wave (2x2 of 32x32x16 MFMA tiles).
__global__ __launch_bounds__(256, 2) void conv_mfma_kernel(
    const float* __restrict__ x, const f16* __restrict__ rp,
    float* __restrict__ out) {
  // weights for one ci-chunk: [khw 9][co_l 128][ci 16], single-buffered
  __shared__ f16 ws[9 * 128 * 16];                    // 36864 B
  // x tile, even/odd iw planes, DOUBLE buffered: [buf 2][p 2][r 9][idx 33][ci 16]
  __shared__ f16 xs[2 * XSBUF];                       // 38048 B  (total 74912 B -> 2 blocks/CU)

  const int t    = threadIdx.x;
  const int lane = t & 63;
  const int wave = t >> 6;
  const int wm   = wave >> 1;   // co 64-half within 128
  const int wn   = wave & 1;    // n 64-half within 128 (= 2 output rows)

  const int blk  = blockIdx.x;  // 512
  const int b    = blk >> 4;
  const int rem  = blk & 15;
  const int co_t = rem >> 3;
  const int oh0  = (rem & 7) << 2;
  const int ih0  = 2 * oh0 - 1;

  const float* xb  = x + (size_t)b * CIN * H_ * W_;
  const f16*   rpb = rp + (size_t)co_t * (16 * 9 * 128 * 16);

  const int iw    = t & 63;        // staging column
  const int rr    = t >> 6;        // staging row group (== wave)
  const int k0    = (lane >> 5) * 8;
  const int ml    = lane & 31;
  const int p_st  = iw & 1;                 // staging plane
  const int idx_st = (iw + p_st) >> 1;      // staging idx within plane

  floatx16 acc[2][2];
#pragma unroll
  for (int mi = 0; mi < 2; ++mi)
#pragma unroll
    for (int nj = 0; nj < 2; ++nj)
#pragma unroll
      for (int i = 0; i < 16; ++i) acc[mi][nj][i] = 0.f;

  // prefetch registers: x = up to 48 fp32 (wave 0), w = 9 x 16B
  float xv[3][2][8];
  half8 wv[9];

  auto load_x = [&](int cc) {
#pragma unroll
    for (int it = 0; it < 3; ++it) {
      const int r = rr + it * 4;            // wave-uniform predicate
      if (r < 9) {
        const int ih = ih0 + r;
        if (ih >= 0) {
          const float* xp = xb + (size_t)cc * 16 * (H_ * W_) + (size_t)ih * W_ + iw;
#pragma unroll
          for (int g = 0; g < 2; ++g)
#pragma unroll
            for (int c = 0; c < 8; ++c)
              xv[it][g][c] = xp[(size_t)(g * 8 + c) * (H_ * W_)];
        } else {
#pragma unroll
          for (int g = 0; g < 2; ++g)
#pragma unroll
            for (int c = 0; c < 8; ++c) xv[it][g][c] = 0.f;
        }
      }
    }
  };

  auto load_w = [&](int cc) {
    const half8* src = (const half8*)(rpb + cc * (9 * 128 * 16));
#pragma unroll
    for (int i = 0; i < 9; ++i) wv[i] = src[t + i * 256];
  };

  auto write_x = [&](int nxt) {
    f16* xd = &xs[nxt * XSBUF + (p_st ? XSP1 : 0)];
#pragma unroll
    for (int it = 0; it < 3; ++it) {
      const int r = rr + it * 4;
      if (r < 9) {
#pragma unroll
        for (int g = 0; g < 2; ++g) {
          half8 v;
#pragma unroll
          for (int c = 0; c < 8; ++c) v[c] = (f16)xv[it][g][c];
          *(half8*)&xd[(r * 33 + idx_st) * 16 + g * 8] = v;
        }
      }
    }
  };

  auto write_w = [&]() {
    half8* dst = (half8*)ws;
#pragma unroll
    for (int i = 0; i < 9; ++i) dst[t + i * 256] = wv[i];
  };

  auto compute = [&](int cur) {
    const f16* xc = &xs[cur * XSBUF];
    __builtin_amdgcn_s_setprio(1);
#pragma unroll
    for (int kh = 0; kh < 3; ++kh) {
#pragma unroll
      for (int kw = 0; kw < 3; ++kw) {
        const int khw = kh * 3 + kw;
        half8 a0 = *(const half8*)&ws[(khw * 128 + wm * 64 + ml) * 16 + k0];
        half8 a1 = *(const half8*)&ws[(khw * 128 + wm * 64 + 32 + ml) * 16 + k0];
        const int pp  = (kw & 1) ^ 1;          // kw=1 -> even plane, else odd
        const int idx = ml + (kw >> 1);        // ow + (kw==2)
        const f16* xpl = xc + (pp ? XSP1 : 0);
#pragma unroll
        for (int nj = 0; nj < 2; ++nj) {
          const int r = 2 * (wn * 2 + nj) + kh;
          half8 bf = *(const half8*)&xpl[(r * 33 + idx) * 16 + k0];
          acc[0][nj] = __builtin_amdgcn_mfma_f32_32x32x16_f16(a0, bf, acc[0][nj], 0, 0, 0);
          acc[1][nj] = __builtin_amdgcn_mfma_f32_32x32x16_f16(a1, bf, acc[1][nj], 0, 0, 0);
        }
      }
    }
    __builtin_amdgcn_s_setprio(0);
  };

  // zero the odd-plane pad column (iw = -1 -> idx 0) of BOTH buffers, once
  if (t < 144) {
    const int r = t >> 4, ci = t & 15;
    xs[0 * XSBUF + XSP1 + (r * 33) * 16 + ci] = (f16)0.f;
    xs[1 * XSBUF + XSP1 + (r * 33) * 16 + ci] = (f16)0.f;
  }

  // prologue: stage cc=0 (latency exposed once, not 16x)
  load_x(0);
  load_w(0);
  write_x(0);
  write_w();
  __syncthreads();

  int cur = 0;
#pragma unroll 1
  for (int cc = 0; cc < 15; ++cc) {
    load_x(cc + 1);                      // ~32-48 scalar fp32 gathers, slow path
    load_w(cc + 1);                      // 9 x dwordx4, L2-resident
    __builtin_amdgcn_sched_barrier(0);   // pin prefetch issue ahead of compute
    compute(cur);                        // pure LDS+MFMA, no vmem -> latency hidden
    write_x(cur ^ 1);                    // idle buffer: no WAR barrier needed
    __syncthreads();                     // all waves done reading ws(cc)
    write_w();                           // ws <- weights(cc+1), 9 ds_write_b128
    __syncthreads();                     // ws and xs[cur^1] visible
    cur ^= 1;
  }
  compute(cur);                          // cc = 15

  // ---- epilogue: C/D col=lane&31 (=ow), row=(reg&3)+8*(reg>>2)+4*(lane>>5) ----
  const int col = ml;
  const int rowbase = (lane >> 5) * 4;
  float* ob = out + ((size_t)b * COUT + co_t * 128 + wm * 64) * (OH * OW);
#pragma unroll
  for (int mi = 0; mi < 2; ++mi) {
#pragma unroll
    for (int nj = 0; nj < 2; ++nj) {
      const int oh = oh0 + wn * 2 + nj;
#pragma unroll
      for (int r = 0; r < 16; ++r) {
        const int row = mi * 32 + (r & 3) + 8 * (r >> 2) + rowbase;
        ob[(size_t)row * (OH * OW) + oh * OW + col] = acc[mi][nj][r];
      }
    }
  }
}

extern "C" void kernel_launch(void* const* d_in, const int* in_sizes, int n_in,
                              void* d_out, int out_size, void* d_ws, size_t ws_size,
                              hipStream_t stream) {
  const float* x = (const float*)d_in[0];   // [32][256][64][64] fp32
  const float* w = (const float*)d_in[1];   // [256][256][3][3]  fp32
  float* out = (float*)d_out;               // [32][256][32][32] fp32
  f16* rp = (f16*)d_ws;                     // 1.18 MB repacked f16 weights

  repack_w_kernel<<<2304, 256, 0, stream>>>(w, rp);
  conv_mfma_kernel<<<512, 256, 0, stream>>>(x, rp, out);
}